// Round 1
// baseline (273.525 us; speedup 1.0000x reference)
//
#include <hip/hip_runtime.h>

#define HH 384
#define WW 640
#define OHH 382
#define OWW 638
#define NPLANES 96
#define NCHUNK 11   // ceil(638 outputs / 62 per wave)
#define NSTRIP 8
#define RPS 48      // output rows per strip

// dssim count  = 16*3*382*638 = 11,698,368
// l1 count     = 16*3*384*640 = 11,796,480

__global__ __launch_bounds__(256) void ssim_main(const float* __restrict__ X,
                                                 const float* __restrict__ Y,
                                                 float* __restrict__ accum) {
    const int wid  = blockIdx.x * 4 + (threadIdx.x >> 6);
    const int lane = threadIdx.x & 63;

    const int p     = wid / (NCHUNK * NSTRIP);
    const int rem   = wid - p * (NCHUNK * NSTRIP);
    const int chunk = rem / NSTRIP;
    const int strip = rem - chunk * NSTRIP;

    const int c = chunk * 62 + lane;          // input column this lane owns
    const bool valid_col = (c < WW);
    const int r0 = strip * RPS;                // first output row
    const int r1 = (r0 + RPS < OHH) ? (r0 + RPS) : OHH;  // exclusive
    const int l1_row_end = (strip == NSTRIP - 1) ? HH : r1;
    const bool l1_col  = (lane < 62) && valid_col;  // count each input col exactly once
    const bool out_col = (lane < 62) && (c < OWW);  // valid SSIM output col

    const size_t pb = (size_t)p * (HH * WW) + c;
    const float* xp = X + pb;
    const float* yp = Y + pb;

    float acc_ssim = 0.f, acc_l1 = 0.f;

    // 3-deep row history of the 5 horizontally-summed quantities (named regs:
    // static indexing only — runtime-indexed arrays would spill to scratch)
    float hx0,hx1,hx2,hy0,hy1,hy2,hxx0,hxx1,hxx2,hyy0,hyy1,hyy2,hxy0,hxy1,hxy2;

#define DOROW(r, RX, RY, RXX, RYY, RXY) do {                                   \
    float xv = 0.f, yv = 0.f;                                                  \
    if (valid_col) { xv = xp[(size_t)(r) * WW]; yv = yp[(size_t)(r) * WW]; }   \
    if (l1_col && (r) < l1_row_end) acc_l1 += fabsf(xv - yv);                  \
    float x1 = __shfl_down(xv, 1), x2 = __shfl_down(xv, 2);                    \
    float y1 = __shfl_down(yv, 1), y2 = __shfl_down(yv, 2);                    \
    RX  = xv + x1 + x2;                                                        \
    RY  = yv + y1 + y2;                                                        \
    RXX = xv*xv + x1*x1 + x2*x2;                                               \
    RYY = yv*yv + y1*y1 + y2*y2;                                               \
    RXY = xv*yv + x1*y1 + x2*y2;                                               \
} while (0)

    DOROW(r0,     hx0, hy0, hxx0, hyy0, hxy0);
    DOROW(r0 + 1, hx1, hy1, hxx1, hyy1, hxy1);

    for (int r = r0; r < r1; ++r) {
        DOROW(r + 2, hx2, hy2, hxx2, hyy2, hxy2);
        const float Sx  = hx0 + hx1 + hx2;
        const float Sy  = hy0 + hy1 + hy2;
        const float Sxx = hxx0 + hxx1 + hxx2;
        const float Syy = hyy0 + hyy1 + hyy2;
        const float Sxy = hxy0 + hxy1 + hxy2;
        const float inv9 = 1.0f / 9.0f;
        const float mu_x = Sx * inv9, mu_y = Sy * inv9;
        const float mu_xx = mu_x * mu_x, mu_yy = mu_y * mu_y, mu_xy = mu_x * mu_y;
        const float sig_x  = Sxx * inv9 - mu_xx;
        const float sig_y  = Syy * inv9 - mu_yy;
        const float sig_xy = Sxy * inv9 - mu_xy;
        const float num = (2.0f * mu_xy + 1e-4f) * (2.0f * sig_xy + 9e-4f);
        const float den = (mu_xx + mu_yy + 1e-4f) * (sig_x + sig_y + 9e-4f);
        float d = (1.0f - num / den) * 0.5f;
        d = fminf(fmaxf(d, 0.0f), 1.0f);
        acc_ssim += out_col ? d : 0.0f;
        hx0 = hx1;  hx1 = hx2;
        hy0 = hy1;  hy1 = hy2;
        hxx0 = hxx1; hxx1 = hxx2;
        hyy0 = hyy1; hyy1 = hyy2;
        hxy0 = hxy1; hxy1 = hxy2;
    }
#undef DOROW

    // wave reduce (64 lanes) then block reduce via LDS, one atomic pair/block
    #pragma unroll
    for (int off = 32; off > 0; off >>= 1) {
        acc_ssim += __shfl_down(acc_ssim, off);
        acc_l1   += __shfl_down(acc_l1, off);
    }
    __shared__ float sm[8];
    const int w = threadIdx.x >> 6;
    if (lane == 0) { sm[w] = acc_ssim; sm[4 + w] = acc_l1; }
    __syncthreads();
    if (threadIdx.x == 0) {
        atomicAdd(&accum[0], sm[0] + sm[1] + sm[2] + sm[3]);
        atomicAdd(&accum[1], sm[4] + sm[5] + sm[6] + sm[7]);
    }
}

__global__ void ssim_finalize(const float* __restrict__ accum, float* __restrict__ out) {
    out[0] = 0.85f * (accum[0] * (1.0f / 11698368.0f))
           + 0.15f * (accum[1] * (1.0f / 11796480.0f));
}

extern "C" void kernel_launch(void* const* d_in, const int* in_sizes, int n_in,
                              void* d_out, int out_size, void* d_ws, size_t ws_size,
                              hipStream_t stream) {
    const float* images = (const float*)d_in[0];
    const float* recon  = (const float*)d_in[1];
    float* accum = (float*)d_ws;
    hipMemsetAsync(accum, 0, 2 * sizeof(float), stream);
    const int nblocks = (NPLANES * NCHUNK * NSTRIP) / 4;  // 8448 waves / 4 = 2112
    ssim_main<<<nblocks, 256, 0, stream>>>(images, recon, accum);
    ssim_finalize<<<1, 1, 0, stream>>>(accum, (float*)d_out);
}

// Round 3
// 242.821 us; speedup vs baseline: 1.1264x; 1.1264x over previous
//
#include <hip/hip_runtime.h>

#define HH 384
#define WW 640
#define OHH 382
#define OWW 638
#define NPLANES 96
#define NCHUNK 3     // col chunks: starts 0,252,504 (16B-aligned), outputs 252/252/134
#define NSTRIP 16    // row strips
#define RPS 24       // output rows per strip (16*24=384>=382; last strip masked)

// ssim denom = 16*3*382*638 = 11,698,368 ; l1 denom = 16*3*384*640 = 11,796,480

typedef float f4 __attribute__((ext_vector_type(4)));

__device__ __forceinline__ f4 win3(f4 v, float n0, float n1) {
    f4 r;
    r.x = v.x + v.y + v.z;
    r.y = v.y + v.z + v.w;
    r.z = v.z + v.w + n0;
    r.w = v.w + n0 + n1;
    return r;
}
__device__ __forceinline__ float rcpf_(float x) { return __builtin_amdgcn_rcpf(x); }

__global__ __launch_bounds__(256, 4) void ssim_main(const float* __restrict__ X,
                                                    const float* __restrict__ Y,
                                                    float* __restrict__ accum) {
    const int lane = threadIdx.x & 63;
    const int wv   = threadIdx.x >> 6;
    const int wid  = __builtin_amdgcn_readfirstlane(blockIdx.x * 4 + wv);

    const int strip = wid & (NSTRIP - 1);
    const int pc    = wid >> 4;
    const int chunk = pc % NCHUNK;
    const int p     = pc / NCHUNK;

    const int a  = chunk * 252;          // chunk load start col (multiple of 4)
    const int c0 = a + lane * 4;         // this lane's first col
    const bool ld_ok = (c0 < WW);        // chunk2 lanes >= 34 load nothing
    const int r0 = strip * RPS;

    const int ssim_end   = (chunk == 2) ? OWW : (a + 252);
    const int l1_end     = (chunk == 2) ? WW  : (a + 252);
    const int l1_row_end = (strip == NSTRIP - 1) ? HH : (r0 + RPS);

    f4 cm, lm;                           // ssim / l1 column ownership masks
    cm.x = (ld_ok && c0 + 0 < ssim_end) ? 1.f : 0.f;
    cm.y = (ld_ok && c0 + 1 < ssim_end) ? 1.f : 0.f;
    cm.z = (ld_ok && c0 + 2 < ssim_end) ? 1.f : 0.f;
    cm.w = (ld_ok && c0 + 3 < ssim_end) ? 1.f : 0.f;
    lm.x = (ld_ok && c0 + 0 < l1_end) ? 1.f : 0.f;
    lm.y = (ld_ok && c0 + 1 < l1_end) ? 1.f : 0.f;
    lm.z = (ld_ok && c0 + 2 < l1_end) ? 1.f : 0.f;
    lm.w = (ld_ok && c0 + 3 < l1_end) ? 1.f : 0.f;

    const size_t pb = (size_t)p * (HH * WW);
    const float* __restrict__ xb = X + pb;
    const float* __restrict__ yb = Y + pb;
    const int fi = (a >> 2) + lane;

    auto ld = [&](const float* b, int row) -> f4 {
        f4 v = {0.f, 0.f, 0.f, 0.f};
        if (ld_ok) v = ((const f4*)(b + (size_t)row * WW))[fi];
        return v;
    };

    f4 acc_s = {0,0,0,0}, acc_l = {0,0,0,0};
    f4 hx0,hy0,hxx0,hyy0,hxy0, hx1,hy1,hxx1,hyy1,hxy1, hx2,hy2,hxx2,hyy2,hxy2;

#define HPROC(xv, yv, HX, HY, HXX, HYY, HXY) do {                              \
    float nx0 = __shfl_down((xv).x, 1), nx1 = __shfl_down((xv).y, 1);          \
    float ny0 = __shfl_down((yv).x, 1), ny1 = __shfl_down((yv).y, 1);          \
    HX  = win3((xv), nx0, nx1);                                                \
    HY  = win3((yv), ny0, ny1);                                                \
    HXX = win3((xv)*(xv), nx0*nx0, nx1*nx1);                                   \
    HYY = win3((yv)*(yv), ny0*ny0, ny1*ny1);                                   \
    HXY = win3((xv)*(yv), nx0*ny0, nx1*ny1);                                   \
} while (0)

#define L1ACC(xv, yv, rowok) do {                                              \
    f4 dmask_ = (rowok) ? lm : (f4){0.f,0.f,0.f,0.f};                          \
    f4 df_ = (xv) - (yv);                                                      \
    df_.x = fabsf(df_.x); df_.y = fabsf(df_.y);                                \
    df_.z = fabsf(df_.z); df_.w = fabsf(df_.w);                                \
    acc_l += df_ * dmask_;                                                     \
} while (0)

    // prologue: rows r0, r0+1 (h-history), row r0+2 staged in (xC,yC)
    f4 xA = ld(xb, r0),     yA = ld(yb, r0);
    f4 xB = ld(xb, r0 + 1), yB = ld(yb, r0 + 1);
    f4 xC = ld(xb, r0 + 2), yC = ld(yb, r0 + 2);
    L1ACC(xA, yA, true);
    HPROC(xA, yA, hx0, hy0, hxx0, hyy0, hxy0);
    L1ACC(xB, yB, true);
    HPROC(xB, yB, hx1, hy1, hxx1, hyy1, hxy1);

#pragma unroll 3
    for (int i = 0; i < RPS; ++i) {
        const int r = r0 + i;
        // prefetch next row (one row lookahead keeps 2KB/wave in flight)
        f4 xN = xC, yN = yC;
        if (i < RPS - 1) {
            int rr = r + 3; if (rr > HH - 1) rr = HH - 1;  // clamp (strip 15 only)
            xN = ld(xb, rr); yN = ld(yb, rr);
        }

        L1ACC(xC, yC, (r + 2) < l1_row_end);
        HPROC(xC, yC, hx2, hy2, hxx2, hyy2, hxy2);

        const float i9 = 1.0f / 9.0f;
        f4 Sx  = hx0 + hx1 + hx2;
        f4 Sy  = hy0 + hy1 + hy2;
        f4 Sxx = hxx0 + hxx1 + hxx2;
        f4 Syy = hyy0 + hyy1 + hyy2;
        f4 Sxy = hxy0 + hxy1 + hxy2;
        f4 mux = Sx * i9, muy = Sy * i9;
        f4 muxx = mux * mux, muyy = muy * muy, muxy = mux * muy;
        f4 sx  = Sxx * i9 - muxx;
        f4 sy  = Syy * i9 - muyy;
        f4 sxy = Sxy * i9 - muxy;
        f4 num = (2.0f * muxy + 1e-4f) * (2.0f * sxy + 9e-4f);
        f4 den = (muxx + muyy + 1e-4f) * (sx + sy + 9e-4f);
        f4 ss;
        ss.x = num.x * rcpf_(den.x);
        ss.y = num.y * rcpf_(den.y);
        ss.z = num.z * rcpf_(den.z);
        ss.w = num.w * rcpf_(den.w);
        f4 d = 0.5f - 0.5f * ss;
        d.x = fminf(fmaxf(d.x, 0.f), 1.f);
        d.y = fminf(fmaxf(d.y, 0.f), 1.f);
        d.z = fminf(fmaxf(d.z, 0.f), 1.f);
        d.w = fminf(fmaxf(d.w, 0.f), 1.f);
        f4 m = (r < OHH) ? cm : (f4){0.f,0.f,0.f,0.f};
        acc_s += d * m;

        hx0 = hx1; hy0 = hy1; hxx0 = hxx1; hyy0 = hyy1; hxy0 = hxy1;
        hx1 = hx2; hy1 = hy2; hxx1 = hxx2; hyy1 = hyy2; hxy1 = hxy2;
        xC = xN; yC = yN;
    }
#undef HPROC
#undef L1ACC

    float s = acc_s.x + acc_s.y + acc_s.z + acc_s.w;
    float l = acc_l.x + acc_l.y + acc_l.z + acc_l.w;
#pragma unroll
    for (int off = 32; off > 0; off >>= 1) {
        s += __shfl_down(s, off);
        l += __shfl_down(l, off);
    }
    __shared__ float sm[8];
    if (lane == 0) { sm[wv] = s; sm[4 + wv] = l; }
    __syncthreads();
    if (threadIdx.x == 0) {
        atomicAdd(&accum[0], sm[0] + sm[1] + sm[2] + sm[3]);
        atomicAdd(&accum[1], sm[4] + sm[5] + sm[6] + sm[7]);
    }
}

__global__ void ssim_finalize(const float* __restrict__ accum, float* __restrict__ out) {
    out[0] = 0.85f * (accum[0] * (1.0f / 11698368.0f))
           + 0.15f * (accum[1] * (1.0f / 11796480.0f));
}

extern "C" void kernel_launch(void* const* d_in, const int* in_sizes, int n_in,
                              void* d_out, int out_size, void* d_ws, size_t ws_size,
                              hipStream_t stream) {
    const float* images = (const float*)d_in[0];
    const float* recon  = (const float*)d_in[1];
    float* accum = (float*)d_ws;
    hipMemsetAsync(accum, 0, 2 * sizeof(float), stream);
    const int nblocks = (NPLANES * NCHUNK * NSTRIP) / 4;  // 4608 waves / 4 = 1152
    ssim_main<<<nblocks, 256, 0, stream>>>(images, recon, accum);
    ssim_finalize<<<1, 1, 0, stream>>>(accum, (float*)d_out);
}

// Round 4
// 231.202 us; speedup vs baseline: 1.1831x; 1.0503x over previous
//
#include <hip/hip_runtime.h>

#define HH 384
#define WW 640
#define OHH 382
#define NPLANES 96
#define NCHUNK 3     // output col ranges [0,256) [256,512) [512,638)
#define NSTRIP 24    // row strips of RPS=16: 24*16 = 384 exact (l1), ssim masked at 382
#define RPS 16
// waves = 96*3*24 = 6912 ; blocks = 1728 = 8*216 (bijective XCD swizzle)
// ssim denom = 16*3*382*638 = 11,698,368 ; l1 denom = 16*3*384*640 = 11,796,480

typedef float f4 __attribute__((ext_vector_type(4)));
typedef float f2 __attribute__((ext_vector_type(2)));

#define C1 0.0162f   // 162 * K1 (K1 = 1e-4)
#define C2 0.1458f   // 162 * K2 (K2 = 9e-4)

__device__ __forceinline__ float rcpf_(float x) { return __builtin_amdgcn_rcpf(x); }

__global__ __launch_bounds__(256, 4) void ssim_main(const float* __restrict__ X,
                                                    const float* __restrict__ Y,
                                                    float* __restrict__ accum) {
    const int lane = threadIdx.x & 63;
    const int wv   = threadIdx.x >> 6;
    int bid = blockIdx.x;
    bid = (bid & 7) * 216 + (bid >> 3);      // XCD-contiguous remap (1728 = 8*216)
    const int wid = __builtin_amdgcn_readfirstlane(bid * 4 + wv);

    const int strip = wid % NSTRIP;          // block = 4 consecutive strips, same (p,chunk)
    const int pc    = wid / NSTRIP;
    const int chunk = pc % NCHUNK;
    const int p     = pc / NCHUNK;

    const int a   = chunk << 8;              // 0, 256, 512
    const int c0  = a + (lane << 2);         // this lane's first output col
    const int l4c = (c0 < 636) ? c0 : 636;   // clamped f4 load col (chunk2 tail lanes dup)
    const int l2c = (c0 + 4 <= 638) ? (c0 + 4) : 632;  // clamped f2 load col
    const int r0  = strip * RPS;

    const int ssim_end = (chunk == 2) ? 638 : (a + 256);
    const int l1_end   = (chunk == 2) ? 640 : (a + 256);

    f4 cm, lm;                               // ssim / l1 ownership masks
    cm.x = (c0 + 0 < ssim_end) ? 1.f : 0.f;
    cm.y = (c0 + 1 < ssim_end) ? 1.f : 0.f;
    cm.z = (c0 + 2 < ssim_end) ? 1.f : 0.f;
    cm.w = (c0 + 3 < ssim_end) ? 1.f : 0.f;
    lm.x = (c0 + 0 < l1_end) ? 1.f : 0.f;
    lm.y = (c0 + 1 < l1_end) ? 1.f : 0.f;
    lm.z = (c0 + 2 < l1_end) ? 1.f : 0.f;
    lm.w = (c0 + 3 < l1_end) ? 1.f : 0.f;

    const size_t pb = (size_t)p * (HH * WW);
    const float* __restrict__ x4p = X + pb + l4c;
    const float* __restrict__ x2p = X + pb + l2c;
    const float* __restrict__ y4p = Y + pb + l4c;
    const float* __restrict__ y2p = Y + pb + l2c;

    f4 accs = {0.f,0.f,0.f,0.f};
    f4 accl = {0.f,0.f,0.f,0.f};

// per-row horizontal pass: u=x+y, v=x-y over 6 cols; H* = 3-wide window sums.
// DO_L1 is compile-time; L1 uses |v| on the 4 owned cols (free from the f4 part).
#define HROW(X4, X2, Y4, Y2, HU, HV, HP, HQ, DO_L1) do {                       \
    float u0=(X4).x+(Y4).x, u1=(X4).y+(Y4).y, u2=(X4).z+(Y4).z,                \
          u3=(X4).w+(Y4).w, u4=(X2).x+(Y2).x, u5=(X2).y+(Y2).y;                \
    float v0=(X4).x-(Y4).x, v1=(X4).y-(Y4).y, v2=(X4).z-(Y4).z,                \
          v3=(X4).w-(Y4).w, v4=(X2).x-(Y2).x, v5=(X2).y-(Y2).y;                \
    if (DO_L1) {                                                               \
        accl.x += fabsf(v0)*lm.x; accl.y += fabsf(v1)*lm.y;                    \
        accl.z += fabsf(v2)*lm.z; accl.w += fabsf(v3)*lm.w;                    \
    }                                                                          \
    float p0=u0*u0,p1=u1*u1,p2=u2*u2,p3=u3*u3,p4=u4*u4,p5=u5*u5;               \
    float q0=v0*v0,q1=v1*v1,q2=v2*v2,q3=v3*v3,q4=v4*v4,q5=v5*v5;               \
    HU = (f4){u0+u1+u2, u1+u2+u3, u2+u3+u4, u3+u4+u5};                         \
    HV = (f4){v0+v1+v2, v1+v2+v3, v2+v3+v4, v3+v4+v5};                         \
    HP = (f4){p0+p1+p2, p1+p2+p3, p2+p3+p4, p3+p4+p5};                         \
    HQ = (f4){q0+q1+q2, q1+q2+q3, q2+q3+q4, q3+q4+q5};                         \
} while (0)

    // prologue: issue all 12 loads (rows r0..r0+2) before any consume
    f4 ax4 = *(const f4*)(x4p + r0*WW);        f2 ax2 = *(const f2*)(x2p + r0*WW);
    f4 ay4 = *(const f4*)(y4p + r0*WW);        f2 ay2 = *(const f2*)(y2p + r0*WW);
    f4 bx4 = *(const f4*)(x4p + (r0+1)*WW);    f2 bx2 = *(const f2*)(x2p + (r0+1)*WW);
    f4 by4 = *(const f4*)(y4p + (r0+1)*WW);    f2 by2 = *(const f2*)(y2p + (r0+1)*WW);
    f4 cx4 = *(const f4*)(x4p + (r0+2)*WW);    f2 cx2 = *(const f2*)(x2p + (r0+2)*WW);
    f4 cy4 = *(const f4*)(y4p + (r0+2)*WW);    f2 cy2 = *(const f2*)(y2p + (r0+2)*WW);

    f4 h0u,h0v,h0p,h0q, h1u,h1v,h1p,h1q;
    HROW(ax4, ax2, ay4, ay2, h0u, h0v, h0p, h0q, true);
    HROW(bx4, bx2, by4, by2, h1u, h1v, h1p, h1q, true);

#pragma unroll
    for (int i = 0; i < RPS; ++i) {
        // prefetch next row (clamped; garbage rows only feed masked outputs)
        int rn = r0 + i + 3; rn = (rn < HH) ? rn : (HH - 1);
        f4 nx4 = *(const f4*)(x4p + rn*WW);    f2 nx2 = *(const f2*)(x2p + rn*WW);
        f4 ny4 = *(const f4*)(y4p + rn*WW);    f2 ny2 = *(const f2*)(y2p + rn*WW);

        f4 hu, hv, hp, hq;
        HROW(cx4, cx2, cy4, cy2, hu, hv, hp, hq, (i <= RPS - 3));  // l1 rows r0+2..r0+15

        const f4 Su = h0u + h1u + hu;
        const f4 Sv = h0v + h1v + hv;
        const f4 Sp = h0p + h1p + hp;   // sum of (x+y)^2
        const f4 Sq = h0q + h1q + hq;   // sum of (x-y)^2

        // scaled SSIM: each factor x162.  4SxSy = Su^2-Sv^2 ; 2(Sx^2+Sy^2) = Su^2+Sv^2
        // 4Sxy = Sp-Sq ; 2(Sxx+Syy) = Sp+Sq
        const f4 A  = Su * Su, B = Sv * Sv;
        const f4 d1 = A - B,   d2 = A + B;
        const f4 t1 = Sp - Sq, t2 = Sp + Sq;
        const f4 n1 = d1 + C1;
        const f4 n2 = 9.f * t1 - d1 + C2;
        const f4 p1v = d2 + C1;
        const f4 p2v = 9.f * t2 - d2 + C2;
        const f4 num = n1 * n2;
        const f4 den = p1v * p2v;
        f4 dd;
        dd.x = 0.5f - 0.5f * num.x * rcpf_(den.x);
        dd.y = 0.5f - 0.5f * num.y * rcpf_(den.y);
        dd.z = 0.5f - 0.5f * num.z * rcpf_(den.z);
        dd.w = 0.5f - 0.5f * num.w * rcpf_(den.w);
        dd.x = fminf(fmaxf(dd.x, 0.f), 1.f);
        dd.y = fminf(fmaxf(dd.y, 0.f), 1.f);
        dd.z = fminf(fmaxf(dd.z, 0.f), 1.f);
        dd.w = fminf(fmaxf(dd.w, 0.f), 1.f);

        f4 cmr = cm;
        if (i >= RPS - 2) {                    // only rows that can hit the 382 bound
            cmr = (r0 + i < OHH) ? cm : (f4){0.f,0.f,0.f,0.f};
        }
        accs += dd * cmr;

        h0u = h1u; h0v = h1v; h0p = h1p; h0q = h1q;
        h1u = hu;  h1v = hv;  h1p = hp;  h1q = hq;
        cx4 = nx4; cx2 = nx2; cy4 = ny4; cy2 = ny2;
    }
#undef HROW

    float s = accs.x + accs.y + accs.z + accs.w;
    float l = accl.x + accl.y + accl.z + accl.w;
#pragma unroll
    for (int off = 32; off > 0; off >>= 1) {
        s += __shfl_down(s, off);
        l += __shfl_down(l, off);
    }
    __shared__ float sm[8];
    if (lane == 0) { sm[wv] = s; sm[4 + wv] = l; }
    __syncthreads();
    if (threadIdx.x == 0) {
        atomicAdd(&accum[0], sm[0] + sm[1] + sm[2] + sm[3]);
        atomicAdd(&accum[1], sm[4] + sm[5] + sm[6] + sm[7]);
    }
}

__global__ void ssim_finalize(const float* __restrict__ accum, float* __restrict__ out) {
    out[0] = 0.85f * (accum[0] * (1.0f / 11698368.0f))
           + 0.15f * (accum[1] * (1.0f / 11796480.0f));
}

extern "C" void kernel_launch(void* const* d_in, const int* in_sizes, int n_in,
                              void* d_out, int out_size, void* d_ws, size_t ws_size,
                              hipStream_t stream) {
    const float* images = (const float*)d_in[0];
    const float* recon  = (const float*)d_in[1];
    float* accum = (float*)d_ws;
    hipMemsetAsync(accum, 0, 2 * sizeof(float), stream);
    const int nblocks = (NPLANES * NCHUNK * NSTRIP) / 4;  // 6912 waves / 4 = 1728
    ssim_main<<<nblocks, 256, 0, stream>>>(images, recon, accum);
    ssim_finalize<<<1, 1, 0, stream>>>(accum, (float*)d_out);
}

// Round 5
// 212.636 us; speedup vs baseline: 1.2864x; 1.0873x over previous
//
#include <hip/hip_runtime.h>

#define HH 384
#define WW 640
#define OHH 382
#define NPLANES 96
#define NCHUNK 3     // load-col starts {0,252,504}, 256 cols each (dwordx4 per lane)
#define NSTRIP 12    // row strips of RPS=32 output rows; 12*32 = 384
#define RPS 32
#define NBLOCKS 864  // 96*3*12 waves / 4 = 864 = 8*108 (bijective XCD swizzle)

// ssim denom = 16*3*382*638 = 11,698,368 ; l1 denom = 16*3*384*640 = 11,796,480

typedef float f4 __attribute__((ext_vector_type(4)));

#define C1 0.0162f   // 162 * K1
#define C2 0.1458f   // 162 * K2

__device__ __forceinline__ float rcpf_(float x) { return __builtin_amdgcn_rcpf(x); }

__global__ __launch_bounds__(256, 3) void ssim_main(const float* __restrict__ X,
                                                    const float* __restrict__ Y,
                                                    float* __restrict__ ws) {
    const int lane = threadIdx.x & 63;
    const int wv   = threadIdx.x >> 6;
    const int bid0 = blockIdx.x;
    const int bid  = (bid0 & 7) * 108 + (bid0 >> 3);   // XCD-contiguous remap
    const int wid  = bid * 4 + wv;                     // block = 4 adjacent strips

    const int strip = wid % NSTRIP;
    const int pc    = wid / NSTRIP;
    const int chunk = pc % NCHUNK;
    const int p     = pc / NCHUNK;

    const int a  = chunk * 252;
    const int c0 = a + (lane << 2);                    // nominal first col
    const int cL = (c0 <= 636) ? c0 : 636;             // clamped load col (chunk2 tail)
    const int r0 = strip * RPS;

    const int ssim_end = (chunk == 2) ? 638 : (a + 252);
    const int l1_end   = (chunk == 2) ? 640 : (a + 252);
    f4 cm, lm;                                         // ownership masks (unclamped c0)
    cm.x = (c0+0 < ssim_end) ? 1.f : 0.f;
    cm.y = (c0+1 < ssim_end) ? 1.f : 0.f;
    cm.z = (c0+2 < ssim_end) ? 1.f : 0.f;
    cm.w = (c0+3 < ssim_end) ? 1.f : 0.f;
    lm.x = (c0+0 < l1_end) ? 1.f : 0.f;
    lm.y = (c0+1 < l1_end) ? 1.f : 0.f;
    lm.z = (c0+2 < l1_end) ? 1.f : 0.f;
    lm.w = (c0+3 < l1_end) ? 1.f : 0.f;

    const size_t pb = (size_t)p * (HH * WW);
    const float* __restrict__ xb = X + pb;
    const float* __restrict__ yb = Y + pb;

#define LD(BASE, ROW) (*(const f4*)((BASE) + (ROW) * WW + cL))

    f4 accs = {0.f,0.f,0.f,0.f};
    f4 accl = {0.f,0.f,0.f,0.f};
    f4 h0u,h0v,h0p,h0q, h1u,h1v,h1p,h1q;

// horizontal pass over this lane's 4 cols (+2 from next lane via shuffle)
#define HROW(XV, YV, HU, HV, HP, HQ, DOL1) do {                                \
    f4 u = (XV) + (YV);                                                        \
    f4 v = (XV) - (YV);                                                        \
    if (DOL1) {                                                                \
        accl.x += fabsf(v.x)*lm.x; accl.y += fabsf(v.y)*lm.y;                  \
        accl.z += fabsf(v.z)*lm.z; accl.w += fabsf(v.w)*lm.w;                  \
    }                                                                          \
    float u4 = __shfl_down(u.x,1), u5 = __shfl_down(u.y,1);                    \
    float v4 = __shfl_down(v.x,1), v5 = __shfl_down(v.y,1);                    \
    f4 pp = u*u, qq = v*v;                                                     \
    float p4 = u4*u4, p5 = u5*u5, q4 = v4*v4, q5 = v5*v5;                      \
    HU = (f4){u.x+u.y+u.z, u.y+u.z+u.w, u.z+u.w+u4, u.w+u4+u5};                \
    HV = (f4){v.x+v.y+v.z, v.y+v.z+v.w, v.z+v.w+v4, v.w+v4+v5};                \
    HP = (f4){pp.x+pp.y+pp.z, pp.y+pp.z+pp.w, pp.z+pp.w+p4, pp.w+p4+p5};       \
    HQ = (f4){qq.x+qq.y+qq.z, qq.y+qq.z+qq.w, qq.z+qq.w+q4, qq.w+q4+q5};       \
} while (0)

    // prologue: rows r0..r0+3 in flight / in regs (2-row lookahead steady state)
    f4 ax = LD(xb, r0),     ay = LD(yb, r0);
    f4 bx = LD(xb, r0 + 1), by = LD(yb, r0 + 1);
    f4 cx = LD(xb, r0 + 2), cy = LD(yb, r0 + 2);
    f4 dx = LD(xb, r0 + 3), dy = LD(yb, r0 + 3);
    HROW(ax, ay, h0u, h0v, h0p, h0q, true);
    HROW(bx, by, h1u, h1v, h1p, h1q, true);

#pragma unroll 2
    for (int i = 0; i < RPS; ++i) {
        // issue row r0+i+4 (clamped; strip 11 dups feed only masked outputs)
        int rn = r0 + i + 4; rn = (rn < HH) ? rn : (HH - 1);
        f4 ex = LD(xb, rn), ey = LD(yb, rn);

        f4 hu, hv, hp, hq;
        HROW(cx, cy, hu, hv, hp, hq, i <= RPS - 3);   // L1 rows r0+2 .. r0+31

        const f4 Su = h0u + h1u + hu;
        const f4 Sv = h0v + h1v + hv;
        const f4 Sp = h0p + h1p + hp;
        const f4 Sq = h0q + h1q + hq;

        // scaled SSIM (each factor x162): 4SxSy=Su^2-Sv^2, 2(Sx^2+Sy^2)=Su^2+Sv^2
        // 4Sxy=Sp-Sq, 2(Sxx+Syy)=Sp+Sq
        const f4 A  = Su * Su, B = Sv * Sv;
        const f4 d1 = A - B,   d2 = A + B;
        const f4 t1 = Sp - Sq, t2 = Sp + Sq;
        const f4 n1  = d1 + C1;
        const f4 n2  = 9.f * t1 - d1 + C2;
        const f4 p1v = d2 + C1;
        const f4 p2v = 9.f * t2 - d2 + C2;
        const f4 num = n1 * n2;
        const f4 den = p1v * p2v;
        f4 dd;
        dd.x = 0.5f - 0.5f * num.x * rcpf_(den.x);
        dd.y = 0.5f - 0.5f * num.y * rcpf_(den.y);
        dd.z = 0.5f - 0.5f * num.z * rcpf_(den.z);
        dd.w = 0.5f - 0.5f * num.w * rcpf_(den.w);
        dd.x = fminf(fmaxf(dd.x, 0.f), 1.f);
        dd.y = fminf(fmaxf(dd.y, 0.f), 1.f);
        dd.z = fminf(fmaxf(dd.z, 0.f), 1.f);
        dd.w = fminf(fmaxf(dd.w, 0.f), 1.f);

        if (r0 + i < OHH) accs += dd * cm;            // wave-uniform gate (strip 11)

        h0u = h1u; h0v = h1v; h0p = h1p; h0q = h1q;
        h1u = hu;  h1v = hv;  h1p = hp;  h1q = hq;
        cx = dx; cy = dy; dx = ex; dy = ey;
    }
#undef HROW
#undef LD

    float s = accs.x + accs.y + accs.z + accs.w;
    float l = accl.x + accl.y + accl.z + accl.w;
#pragma unroll
    for (int off = 32; off > 0; off >>= 1) {
        s += __shfl_down(s, off);
        l += __shfl_down(l, off);
    }
    __shared__ float sm[8];
    if (lane == 0) { sm[wv] = s; sm[4 + wv] = l; }
    __syncthreads();
    if (threadIdx.x == 0) {
        // pure stores (no init needed; re-poison-safe), slot by original blockIdx
        ws[bid0 * 2 + 0] = sm[0] + sm[1] + sm[2] + sm[3];
        ws[bid0 * 2 + 1] = sm[4] + sm[5] + sm[6] + sm[7];
    }
}

__global__ __launch_bounds__(256) void ssim_finalize(const float* __restrict__ ws,
                                                     float* __restrict__ out) {
    const int t = threadIdx.x;
    float s = 0.f, l = 0.f;
    for (int j = t; j < NBLOCKS; j += 256) {
        s += ws[2*j];
        l += ws[2*j + 1];
    }
#pragma unroll
    for (int off = 32; off > 0; off >>= 1) {
        s += __shfl_down(s, off);
        l += __shfl_down(l, off);
    }
    __shared__ float sm[8];
    const int w = t >> 6, lane = t & 63;
    if (lane == 0) { sm[w] = s; sm[4 + w] = l; }
    __syncthreads();
    if (t == 0) {
        float S = sm[0] + sm[1] + sm[2] + sm[3];
        float L = sm[4] + sm[5] + sm[6] + sm[7];
        out[0] = 0.85f * (S * (1.0f / 11698368.0f))
               + 0.15f * (L * (1.0f / 11796480.0f));
    }
}

extern "C" void kernel_launch(void* const* d_in, const int* in_sizes, int n_in,
                              void* d_out, int out_size, void* d_ws, size_t ws_size,
                              hipStream_t stream) {
    const float* images = (const float*)d_in[0];
    const float* recon  = (const float*)d_in[1];
    float* ws = (float*)d_ws;
    ssim_main<<<NBLOCKS, 256, 0, stream>>>(images, recon, ws);
    ssim_finalize<<<1, 256, 0, stream>>>(ws, (float*)d_out);
}